// Round 1
// baseline (210.462 us; speedup 1.0000x reference)
//
#include <hip/hip_runtime.h>

#define BB 64
#define NN 512
#define DD 128
#define TT 8
#define NEG_SLOPE 0.2f

// ---------------------------------------------------------------------------
// Kernel 1: s_src[b,n,t] = sum_d src[b,n,d] * a[t*2D + d]
//           s_dst[b,n,t] = sum_d dst[b,n,d] * a[t*2D + D + d]
// One wave (64 lanes) per row; 4 waves / block. Rows 0..B*N-1 are src rows,
// rows B*N..2*B*N-1 are dst rows. Output s: [2*B*N, T] f32 in workspace.
// ---------------------------------------------------------------------------
__global__ __launch_bounds__(256) void precompute_scores(
    const float* __restrict__ src, const float* __restrict__ dst,
    const float* __restrict__ a, float* __restrict__ s) {
  __shared__ float a_lds[2 * DD * TT];  // 2048 floats = 8 KiB
  const int tid = threadIdx.x;
  for (int i = tid; i < 2 * DD * TT; i += 256) a_lds[i] = a[i];
  __syncthreads();

  const int wave = tid >> 6;
  const int lane = tid & 63;
  const long row = (long)blockIdx.x * 4 + wave;  // 0 .. 2*B*N-1
  const long half = (long)BB * NN;

  const float* base;
  int aoff;
  if (row < half) {
    base = src + row * DD;
    aoff = 0;
  } else {
    base = dst + (row - half) * DD;
    aoff = DD;
  }

  // lane l covers d = 2l, 2l+1 (coalesced 8B loads)
  const float2 x = *(const float2*)(base + 2 * lane);

  float p[TT];
#pragma unroll
  for (int t = 0; t < TT; ++t) {
    p[t] = x.x * a_lds[t * 2 * DD + aoff + 2 * lane] +
           x.y * a_lds[t * 2 * DD + aoff + 2 * lane + 1];
  }

  // butterfly wave-64 reduction; all lanes end with the full sum
#pragma unroll
  for (int t = 0; t < TT; ++t) {
    float v = p[t];
#pragma unroll
    for (int o = 32; o >= 1; o >>= 1) v += __shfl_xor(v, o, 64);
    p[t] = v;
  }

  if (lane == 0) {
#pragma unroll
    for (int t = 0; t < TT; ++t) s[row * TT + t] = p[t];
  }
}

// ---------------------------------------------------------------------------
// Kernel 2: out[b,i,j] = leakyrelu( (edges>=0) ? s_src[b,i,e] + s_dst[b,j,e]
//                                              : 0 )
// One block per (b,i) row: 128 threads x 4 j each (int4 load / float4 store).
// s_src row (8 floats) staged in LDS (8 words -> 8 distinct banks, no
// conflicts). s_dst gathered from global: per-b slice is 16 KiB, L1/L2-hit.
// ---------------------------------------------------------------------------
__global__ __launch_bounds__(128) void edge_attention(
    const int* __restrict__ edges, const float* __restrict__ s_src,
    const float* __restrict__ s_dst, float* __restrict__ out) {
  const int row = blockIdx.x;    // b*N + i
  const int b = row >> 9;        // N = 512

  __shared__ float ssrc[TT];
  if (threadIdx.x < TT) ssrc[threadIdx.x] = s_src[(long)row * TT + threadIdx.x];
  __syncthreads();

  const int j0 = threadIdx.x * 4;
  const long base = (long)row * NN + j0;
  const int4 e4 = *(const int4*)(edges + base);
  const float* __restrict__ sd = s_dst + (long)b * NN * TT;

  const int ee[4] = {e4.x, e4.y, e4.z, e4.w};
  float oo[4];
#pragma unroll
  for (int m = 0; m < 4; ++m) {
    const int e = ee[m];
    const int k = e < 0 ? 0 : e;  // e >= 0 already < T per reference
    const float g = ssrc[k] + sd[(j0 + m) * TT + k];
    const float v = e < 0 ? 0.0f : g;
    oo[m] = v >= 0.0f ? v : NEG_SLOPE * v;
  }

  const float4 o = {oo[0], oo[1], oo[2], oo[3]};
  *(float4*)(out + base) = o;
}

// ---------------------------------------------------------------------------
extern "C" void kernel_launch(void* const* d_in, const int* in_sizes, int n_in,
                              void* d_out, int out_size, void* d_ws, size_t ws_size,
                              hipStream_t stream) {
  const float* src = (const float*)d_in[0];
  const float* dst = (const float*)d_in[1];
  const int* edges = (const int*)d_in[2];
  const float* a = (const float*)d_in[3];
  float* out = (float*)d_out;

  float* s = (float*)d_ws;                 // [2*B*N, T] = 2 MiB
  float* s_src = s;
  float* s_dst = s + (long)BB * NN * TT;

  // Kernel 1: 2*B*N rows, 4 waves/block
  const int rows = 2 * BB * NN;            // 65536
  precompute_scores<<<rows / 4, 256, 0, stream>>>(src, dst, a, s);

  // Kernel 2: one block per (b,i) row
  edge_attention<<<BB * NN, 128, 0, stream>>>(edges, s_src, s_dst, out);
}

// Round 3
// 155.639 us; speedup vs baseline: 1.3522x; 1.3522x over previous
//
#include <hip/hip_runtime.h>

#define BB 64
#define NN 512
#define DD 128
#define TT 8
#define NEG_SLOPE 0.2f

typedef float f32x4 __attribute__((ext_vector_type(4)));
typedef int i32x4 __attribute__((ext_vector_type(4)));

// ---------------------------------------------------------------------------
// Kernel 1: projections.
//   s_src [b*N+n][t]          = sum_d src[b,n,d] * a[t*2D + d]
//   s_dstT[b][t][n] (t-major) = sum_d dst[b,n,d] * a[t*2D + D + d]
// 4 rows per wave: 16 lanes/row, 8 d-elements per lane, a[] held in regs
// (amortized over 16 rows via half/pass loops). Reduction: xor 1,2,4 on all
// 8 t (partial over 8-lane groups), select p[sl&7], xor 8. Lane sl<8 of each
// 16-lane group holds the full sum for t=sl.
// ---------------------------------------------------------------------------
__global__ __launch_bounds__(256) void precompute_scores(
    const float* __restrict__ src, const float* __restrict__ dst,
    const float* __restrict__ a, float* __restrict__ s_src,
    float* __restrict__ s_dstT) {
  const int tid = threadIdx.x;
  const int wave = tid >> 6;
  const int lane = tid & 63;
  const int sub = lane >> 4;   // which of 4 rows in this wave
  const int sl = lane & 15;    // 16-lane slice within row
  const int dd0 = sl * 8;      // this lane's d-chunk

#pragma unroll
  for (int half = 0; half < 2; ++half) {
    const float* __restrict__ X = half ? dst : src;
    // a slice for this lane: ar[t][0..7]
    float ar[TT][8];
#pragma unroll
    for (int t = 0; t < TT; ++t) {
      const f32x4 a0 = *(const f32x4*)(a + t * 2 * DD + half * DD + dd0);
      const f32x4 a1 = *(const f32x4*)(a + t * 2 * DD + half * DD + dd0 + 4);
      ar[t][0] = a0.x; ar[t][1] = a0.y; ar[t][2] = a0.z; ar[t][3] = a0.w;
      ar[t][4] = a1.x; ar[t][5] = a1.y; ar[t][6] = a1.z; ar[t][7] = a1.w;
    }
#pragma unroll
    for (int pass = 0; pass < 2; ++pass) {
      const int r = pass * 16384 + blockIdx.x * 16 + wave * 4 + sub;  // 0..32767
      const f32x4 x0 = *(const f32x4*)(X + (long)r * DD + dd0);
      const f32x4 x1 = *(const f32x4*)(X + (long)r * DD + dd0 + 4);

      float p[TT];
#pragma unroll
      for (int t = 0; t < TT; ++t) {
        p[t] = x0.x * ar[t][0] + x0.y * ar[t][1] + x0.z * ar[t][2] +
               x0.w * ar[t][3] + x1.x * ar[t][4] + x1.y * ar[t][5] +
               x1.z * ar[t][6] + x1.w * ar[t][7];
      }
      // reduce across 8-lane subgroups for all t
#pragma unroll
      for (int t = 0; t < TT; ++t) {
        p[t] += __shfl_xor(p[t], 1, 64);
        p[t] += __shfl_xor(p[t], 2, 64);
        p[t] += __shfl_xor(p[t], 4, 64);
      }
      // lane keeps t = sl&7
      const int tk = sl & 7;
      float v = p[0];
      v = tk == 1 ? p[1] : v;
      v = tk == 2 ? p[2] : v;
      v = tk == 3 ? p[3] : v;
      v = tk == 4 ? p[4] : v;
      v = tk == 5 ? p[5] : v;
      v = tk == 6 ? p[6] : v;
      v = tk == 7 ? p[7] : v;
      // combine the two 8-lane halves of this row's 16-lane group
      v += __shfl_xor(v, 8, 64);

      if (sl < 8) {
        if (half == 0) {
          s_src[(long)r * TT + sl] = v;  // contiguous per wave
        } else {
          const int b = r >> 9, n = r & 511;
          s_dstT[(long)b * NN * TT + sl * NN + n] = v;
        }
      }
    }
  }
}

// ---------------------------------------------------------------------------
// Kernel 2: out[b,i,j] = leakyrelu( (e>=0) ? s_src[b,i,e] + s_dst[b,j,e] : 0 )
// Block = (b, 32-row i-tile), 256 threads. s_dstT[b] (16 KB) + 32 s_src rows
// (1 KB) staged in LDS via straight coalesced copies. Edges int4 / out float4
// (16 B/lane). Gather sdt[k*512+j] is LDS (8-way conflict, hidden under HBM).
// ---------------------------------------------------------------------------
__global__ __launch_bounds__(256) void edge_attention(
    const int* __restrict__ edges, const float* __restrict__ s_src,
    const float* __restrict__ s_dstT, float* __restrict__ out) {
  __shared__ float sdt[TT * NN];   // [t][j] 16 KB
  __shared__ float ssc[32 * TT];   // [local row][t] 1 KB

  const int tid = threadIdx.x;
  const int b = blockIdx.x >> 4;         // 16 i-tiles per b
  const int i0 = (blockIdx.x & 15) * 32;

  // stage s_dstT[b] : 4096 floats = 1024 float4
  const f32x4* __restrict__ g_sdt = (const f32x4*)(s_dstT + (long)b * NN * TT);
  f32x4* __restrict__ l_sdt = (f32x4*)sdt;
#pragma unroll
  for (int q = 0; q < 4; ++q) l_sdt[q * 256 + tid] = g_sdt[q * 256 + tid];

  // stage 32 rows of s_src: 256 floats = 64 float4
  if (tid < 64) {
    ((f32x4*)ssc)[tid] =
        ((const f32x4*)(s_src + ((long)b * NN + i0) * TT))[tid];
  }
  __syncthreads();

  const int rsub = tid >> 7;         // 0/1: which row this half-block does
  const int j0 = (tid & 127) * 4;

#pragma unroll 4
  for (int it = 0; it < 16; ++it) {
    const int r = it * 2 + rsub;                   // local row 0..31
    const long base = ((long)(b * NN + i0 + r)) * NN + j0;
    const i32x4 e4 = *(const i32x4*)(edges + base);
    const float* __restrict__ sr = ssc + r * TT;

    const int ee[4] = {e4.x, e4.y, e4.z, e4.w};
    float oo[4];
#pragma unroll
    for (int m = 0; m < 4; ++m) {
      const int e = ee[m];
      const int k = e < 0 ? 0 : e;  // e>=0 is already < T
      const float g = sr[k] + sdt[k * NN + j0 + m];
      const float v = e < 0 ? 0.0f : g;
      oo[m] = v >= 0.0f ? v : NEG_SLOPE * v;
    }
    const f32x4 o = {oo[0], oo[1], oo[2], oo[3]};
    __builtin_nontemporal_store(o, (f32x4*)(out + base));
  }
}

// ---------------------------------------------------------------------------
extern "C" void kernel_launch(void* const* d_in, const int* in_sizes, int n_in,
                              void* d_out, int out_size, void* d_ws, size_t ws_size,
                              hipStream_t stream) {
  const float* src = (const float*)d_in[0];
  const float* dst = (const float*)d_in[1];
  const int* edges = (const int*)d_in[2];
  const float* a = (const float*)d_in[3];
  float* out = (float*)d_out;

  float* s_src = (float*)d_ws;                       // [B*N, T]   1 MiB
  float* s_dstT = s_src + (long)BB * NN * TT;        // [B, T, N]  1 MiB

  // Kernel 1: 65536 rows total; 16 rows/block-pass, 4 passes -> 1024 blocks
  precompute_scores<<<1024, 256, 0, stream>>>(src, dst, a, s_src, s_dstT);

  // Kernel 2: (b, i-tile of 32) per block
  edge_attention<<<BB * 16, 256, 0, stream>>>(edges, s_src, s_dstT, out);
}